// Round 2
// baseline (2644.781 us; speedup 1.0000x reference)
//
#include <hip/hip_runtime.h>
#include <hip/hip_bf16.h>

// Problem constants (from reference): B=8, T=4096, E=16, H=64
#define BB 8
#define TT 4096
#define EE 16
#define HH 64
#define TSPLIT 4   // t-range split for colsum (atomicAdd partials into D)
#define SSPLIT 4   // s-range split for out pass (separate ws slices, then reduce)

static __device__ __forceinline__ float pow_neg16th_exp(float dot) {
    // exp( dot^(-1/16) ) ; dot > 0 guaranteed by construction (U(0,1) inputs).
    // HW transcendentals: v_log_f32 / v_exp_f32 via amdgcn builtins
    // (NOT __exp2f/__log2f — those collide with glibc macros under HIP).
    float S = __builtin_amdgcn_exp2f(__builtin_amdgcn_logf(dot) * (-1.0f / 16.0f));
    return __builtin_amdgcn_exp2f(S * 1.44269504f);
}

// ---- kernel 0: zero D -------------------------------------------------------
__global__ void zeroD_kernel(float* __restrict__ D) {
    int i = blockIdx.x * 256 + threadIdx.x;
    if (i < BB * TT) D[i] = 0.0f;
}

// ---- kernel 1: Q = x@Wq, K = x@Wk ------------------------------------------
// one thread per (row, h); 4 rows per 256-thread block
__global__ __launch_bounds__(256) void proj_kernel(
        const float* __restrict__ x, const float* __restrict__ Wq,
        const float* __restrict__ Wk, float* __restrict__ Q, float* __restrict__ K) {
    int tid = threadIdx.x;
    int row = blockIdx.x * 4 + (tid >> 6);
    int h = tid & 63;
    const float* xr = x + (size_t)row * EE;
    float q = 0.f, k = 0.f;
#pragma unroll
    for (int e = 0; e < EE; ++e) {
        float xv = xr[e];
        q += xv * Wq[e * HH + h];
        k += xv * Wk[e * HH + h];
    }
    Q[(size_t)row * HH + h] = q;
    K[(size_t)row * HH + h] = k;
}

// ---- kernel 2: D[b,s] = sum_t exp((q_t . k_s)^(-1/16)) ---------------------
// lane owns s (64 s per wave, k_s in 64 VGPRs); q_t is wave-uniform -> s_load.
// grid: (T/64, B, TSPLIT); 4 waves per block each take a t-subrange.
__global__ __launch_bounds__(256) void colsum_kernel(
        const float* __restrict__ Q, const float* __restrict__ K,
        float* __restrict__ D) {
    int lane = threadIdx.x & 63;
    int w = threadIdx.x >> 6;
    int b = blockIdx.y;
    int s = blockIdx.x * 64 + lane;

    const float* krow = K + ((size_t)b * TT + s) * HH;
    float k[HH];
#pragma unroll
    for (int j = 0; j < HH; j += 4) {
        float4 kv = *(const float4*)(krow + j);
        k[j] = kv.x; k[j + 1] = kv.y; k[j + 2] = kv.z; k[j + 3] = kv.w;
    }

    const int TL = TT / (TSPLIT * 4);             // 256 t per wave
    int t0 = (blockIdx.z * 4 + w) * TL;
    const float* qbase = Q + (size_t)b * TT * HH;

    float dsum = 0.f;
    for (int t = t0; t < t0 + TL; ++t) {
        const float* qrow = qbase + (size_t)t * HH;   // wave-uniform address
        float d0 = 0.f, d1 = 0.f, d2 = 0.f, d3 = 0.f;
#pragma unroll
        for (int j = 0; j < HH; j += 4) {
            d0 += qrow[j]     * k[j];
            d1 += qrow[j + 1] * k[j + 1];
            d2 += qrow[j + 2] * k[j + 2];
            d3 += qrow[j + 3] * k[j + 3];
        }
        float dot = (d0 + d1) + (d2 + d3);
        dsum += pow_neg16th_exp(dot);
    }
    atomicAdd(&D[(size_t)b * TT + s], dsum);
}

// ---- kernel 3: out_part[z][b,t,:] = sum_{s in slice z} exp(S_ts)/D_s * k_s --
// lane owns t (q_t in 64 VGPRs, acc in 64 VGPRs); k_s, D_s wave-uniform.
// grid: (T/256, B, SSPLIT); 4 waves per block cover 4 t-tiles, same s-slice.
__global__ __launch_bounds__(256) void out_kernel(
        const float* __restrict__ Q, const float* __restrict__ K,
        const float* __restrict__ D, float* __restrict__ OP) {
    int lane = threadIdx.x & 63;
    int w = threadIdx.x >> 6;
    int b = blockIdx.y;
    int z = blockIdx.z;
    int t = blockIdx.x * 256 + w * 64 + lane;

    const float* qrow = Q + ((size_t)b * TT + t) * HH;
    float q[HH];
#pragma unroll
    for (int j = 0; j < HH; j += 4) {
        float4 qv = *(const float4*)(qrow + j);
        q[j] = qv.x; q[j + 1] = qv.y; q[j + 2] = qv.z; q[j + 3] = qv.w;
    }

    float acc[HH];
#pragma unroll
    for (int j = 0; j < HH; ++j) acc[j] = 0.f;

    const int SL = TT / SSPLIT;                   // 1024 s per slice
    int s0 = z * SL;
    const float* kbase = K + (size_t)b * TT * HH;
    const float* Db = D + (size_t)b * TT;

    for (int s = s0; s < s0 + SL; ++s) {
        const float* krow = kbase + (size_t)s * HH;   // wave-uniform address
        float d0 = 0.f, d1 = 0.f, d2 = 0.f, d3 = 0.f;
#pragma unroll
        for (int j = 0; j < HH; j += 4) {
            d0 += q[j]     * krow[j];
            d1 += q[j + 1] * krow[j + 1];
            d2 += q[j + 2] * krow[j + 2];
            d3 += q[j + 3] * krow[j + 3];
        }
        float dot = (d0 + d1) + (d2 + d3);
        float wgt = pow_neg16th_exp(dot) / Db[s];
#pragma unroll
        for (int j = 0; j < HH; ++j) acc[j] += wgt * krow[j];
    }

    float* op = OP + (((size_t)z * BB + b) * TT + t) * HH;
#pragma unroll
    for (int j = 0; j < HH; ++j) op[j] = acc[j];
}

// ---- kernel 4: out = sum_z out_part[z] -------------------------------------
__global__ __launch_bounds__(256) void reduce_kernel(
        const float* __restrict__ OP, float* __restrict__ out) {
    size_t i = (size_t)blockIdx.x * 256 + threadIdx.x;   // float4 units
    const size_t N4 = (size_t)BB * TT * HH / 4;
    if (i >= N4) return;
    const float4* p = (const float4*)OP;
    float4 a = p[i];
#pragma unroll
    for (int z = 1; z < SSPLIT; ++z) {
        float4 v = p[(size_t)z * N4 + i];
        a.x += v.x; a.y += v.y; a.z += v.z; a.w += v.w;
    }
    ((float4*)out)[i] = a;
}

extern "C" void kernel_launch(void* const* d_in, const int* in_sizes, int n_in,
                              void* d_out, int out_size, void* d_ws, size_t ws_size,
                              hipStream_t stream) {
    const float* x  = (const float*)d_in[0];
    const float* Wq = (const float*)d_in[1];
    const float* Wk = (const float*)d_in[2];
    // d_in[3] (Wv) is unused: reference computes v = x @ Wk (faithful quirk).

    float* ws = (float*)d_ws;
    float* Q  = ws;                                     // B*T*H = 2,097,152
    float* K  = Q + (size_t)BB * TT * HH;               // 2,097,152
    float* D  = K + (size_t)BB * TT * HH;               // B*T = 32,768
    float* OP = D + (size_t)BB * TT;                    // SSPLIT * B*T*H = 8,388,608
    float* out = (float*)d_out;

    zeroD_kernel<<<(BB * TT + 255) / 256, 256, 0, stream>>>(D);
    proj_kernel<<<BB * TT / 4, 256, 0, stream>>>(x, Wq, Wk, Q, K);
    colsum_kernel<<<dim3(TT / 64, BB, TSPLIT), 256, 0, stream>>>(Q, K, D);
    out_kernel<<<dim3(TT / 256, BB, SSPLIT), 256, 0, stream>>>(Q, K, D, OP);
    reduce_kernel<<<(BB * TT * HH / 4 + 255) / 256, 256, 0, stream>>>(OP, out);
}

// Round 3
// 461.927 us; speedup vs baseline: 5.7255x; 5.7255x over previous
//
#include <hip/hip_runtime.h>
#include <hip/hip_bf16.h>

// Problem constants (from reference): B=8, T=4096, E=16, H=64
#define BB 8
#define TT 4096
#define EE 16
#define HH 64
#define TSPLIT 8   // t-range split for colsum
#define SSPLIT 4   // s-range split for out pass (ws partial slices, then reduce)

typedef __attribute__((ext_vector_type(8))) __bf16 bf16x8;  // MFMA A/B frag (4 VGPRs)
typedef __attribute__((ext_vector_type(4))) float f32x4;    // MFMA C/D frag

static __device__ __forceinline__ float pow_neg16th_exp(float dot) {
    // exp( dot^(-1/16) ), dot > 0. v_log_f32/v_exp_f32 are base-2: 2^(log2(d)*-1/16) = d^-1/16.
    float S = __builtin_amdgcn_exp2f(__builtin_amdgcn_logf(dot) * (-1.0f / 16.0f));
    return __builtin_amdgcn_exp2f(S * 1.44269504f);
}

// ---- kernel 0: zero D -------------------------------------------------------
__global__ void zeroD_kernel(float* __restrict__ D) {
    int i = blockIdx.x * 256 + threadIdx.x;
    if (i < BB * TT) D[i] = 0.0f;
}

// ---- kernel 1: Qb = bf16(x@Wq), Kb = bf16(x@Wk), Kf = fp32(x@Wk) -----------
__global__ __launch_bounds__(256) void proj_kernel(
        const float* __restrict__ x, const float* __restrict__ Wq,
        const float* __restrict__ Wk,
        __bf16* __restrict__ Qb, __bf16* __restrict__ Kb, float* __restrict__ Kf) {
    int tid = threadIdx.x;
    int row = blockIdx.x * 4 + (tid >> 6);
    int h = tid & 63;
    const float* xr = x + (size_t)row * EE;
    float q = 0.f, k = 0.f;
#pragma unroll
    for (int e = 0; e < EE; ++e) {
        float xv = xr[e];
        q += xv * Wq[e * HH + h];
        k += xv * Wk[e * HH + h];
    }
    size_t idx = (size_t)row * HH + h;
    Qb[idx] = (__bf16)q;
    Kb[idx] = (__bf16)k;
    Kf[idx] = k;
}

// ---- kernel 2: D[b,s] += sum_t exp((q_t.k_s)^(-1/16)) via MFMA -------------
// Wave handles one 16-wide s-tile, iterates 16-wide t-tiles over a t-chunk.
// S-tile: A=Qb (m=t), B=Kb (n=s), K-dim = H = 64 (2 chained 16x16x32 MFMAs).
// C/D layout (m89-verified): col = lane&15 (=s), row = (lane>>4)*4 + reg (=t).
__global__ __launch_bounds__(256) void colsum_mfma(
        const __bf16* __restrict__ Qb, const __bf16* __restrict__ Kb,
        float* __restrict__ D) {
    int lane = threadIdx.x & 63;
    int w = threadIdx.x >> 6;
    int quad = lane >> 4;
    int l15 = lane & 15;
    int b = blockIdx.y;
    int s0 = blockIdx.x * 64 + w * 16;

    const __bf16* Qbb = Qb + (size_t)b * TT * HH;
    const __bf16* Kbb = Kb + (size_t)b * TT * HH;

    // B-frag: lane holds B[k=quad*8+j][n=l15] = Kb[s0+l15][h=quad*8+j(+32)]
    const __bf16* krow = Kbb + (size_t)(s0 + l15) * HH + quad * 8;
    bf16x8 bk0 = *(const bf16x8*)(krow);
    bf16x8 bk1 = *(const bf16x8*)(krow + 32);

    const int TL = TT / TSPLIT;                 // 512 t per wave
    int t0 = blockIdx.z * TL;
    float csum = 0.f;
    for (int tt = 0; tt < TL; tt += 16) {
        // A-frag: lane holds A[m=l15][k=quad*8+j] = Qb[t0+tt+l15][h=quad*8+j(+32)]
        const __bf16* qrow = Qbb + (size_t)(t0 + tt + l15) * HH + quad * 8;
        bf16x8 a0 = *(const bf16x8*)(qrow);
        bf16x8 a1 = *(const bf16x8*)(qrow + 32);
        f32x4 c = {0.f, 0.f, 0.f, 0.f};
        c = __builtin_amdgcn_mfma_f32_16x16x32_bf16(a0, bk0, c, 0, 0, 0);
        c = __builtin_amdgcn_mfma_f32_16x16x32_bf16(a1, bk1, c, 0, 0, 0);
        csum += pow_neg16th_exp(c[0]) + pow_neg16th_exp(c[1])
              + pow_neg16th_exp(c[2]) + pow_neg16th_exp(c[3]);
    }
    // lane holds partial colsum for s = s0+l15 over its quad's 4 t-rows x TL/16 tiles.
    csum += __shfl_xor(csum, 16, 64);
    csum += __shfl_xor(csum, 32, 64);
    if (quad == 0) atomicAdd(&D[(size_t)b * TT + s0 + l15], csum);
}

// ---- kernel 3: VsT[b][h][s] = bf16(Kf[b][s][h] / D[b][s]) ------------------
// Transposed so the PV B-frag load (8 consecutive s for fixed h) is contiguous.
__global__ __launch_bounds__(256) void vscale_kernel(
        const float* __restrict__ Kf, const float* __restrict__ D,
        __bf16* __restrict__ VsT) {
    __shared__ float tile[64][65];
    int b = blockIdx.y;
    int s0 = blockIdx.x * 64;
    int c = threadIdx.x & 63;
    int rr = threadIdx.x >> 6;
    const float* Kbase = Kf + ((size_t)b * TT + s0) * HH;
    const float* Db = D + (size_t)b * TT + s0;
#pragma unroll
    for (int i = rr; i < 64; i += 4)
        tile[i][c] = Kbase[(size_t)i * HH + c] / Db[i];   // tile[s_local][h]
    __syncthreads();
    __bf16* Vb = VsT + (size_t)b * HH * TT;
#pragma unroll
    for (int i = rr; i < 64; i += 4)
        Vb[(size_t)i * TT + s0 + c] = (__bf16)tile[c][i]; // VsT[h=i][s=s0+c]
}

// ---- kernel 4: OP[z][b][t][h] = sum_{s in slice z} exp(S_ts) * VsT[h][s] ---
// Per wave: one 16-row t-tile, 16 fp32 accumulators (t16 x h64), loop s by 32:
//   S-tile MFMA -> exp -> bf16 -> per-wave LDS (C-layout -> A-layout) -> 4 PV MFMAs.
// Wave-internal DS ops are in-order; lgkmcnt(0) suffices, no barrier.
__global__ __launch_bounds__(256) void out_mfma(
        const __bf16* __restrict__ Qb, const __bf16* __restrict__ Kb,
        const __bf16* __restrict__ VsT, float* __restrict__ OP) {
    __shared__ __bf16 Etile[4][16 * 40];   // per-wave 16 x 32, row stride 40 (conflict pad)
    int lane = threadIdx.x & 63;
    int w = threadIdx.x >> 6;
    int quad = lane >> 4;
    int l15 = lane & 15;
    int b = blockIdx.y;
    int z = blockIdx.z;
    int t0 = (blockIdx.x * 4 + w) * 16;

    const __bf16* Qbb = Qb + (size_t)b * TT * HH;
    const __bf16* Kbb = Kb + (size_t)b * TT * HH;
    const __bf16* Vbb = VsT + (size_t)b * HH * TT;

    const __bf16* qrow = Qbb + (size_t)(t0 + l15) * HH + quad * 8;
    bf16x8 aq0 = *(const bf16x8*)(qrow);
    bf16x8 aq1 = *(const bf16x8*)(qrow + 32);

    f32x4 acc0 = {0.f,0.f,0.f,0.f}, acc1 = {0.f,0.f,0.f,0.f};
    f32x4 acc2 = {0.f,0.f,0.f,0.f}, acc3 = {0.f,0.f,0.f,0.f};

    __bf16* E = Etile[w];
    const int SL = TT / SSPLIT;                 // 1024 s per slice
    int send = z * SL + SL;
    for (int s = z * SL; s < send; s += 32) {
#pragma unroll
        for (int sub = 0; sub < 2; ++sub) {
            const __bf16* krow = Kbb + (size_t)(s + sub * 16 + l15) * HH + quad * 8;
            bf16x8 bk0 = *(const bf16x8*)(krow);
            bf16x8 bk1 = *(const bf16x8*)(krow + 32);
            f32x4 c = {0.f, 0.f, 0.f, 0.f};
            c = __builtin_amdgcn_mfma_f32_16x16x32_bf16(aq0, bk0, c, 0, 0, 0);
            c = __builtin_amdgcn_mfma_f32_16x16x32_bf16(aq1, bk1, c, 0, 0, 0);
            // C layout: rows t_local=quad*4+r, col s_local=sub*16+l15
#pragma unroll
            for (int r = 0; r < 4; ++r)
                E[(quad * 4 + r) * 40 + sub * 16 + l15] = (__bf16)pow_neg16th_exp(c[r]);
        }
        __builtin_amdgcn_s_waitcnt(0xc07f);     // lgkmcnt(0): wave's LDS writes visible
        // A-frag from E: A[m=l15][k=quad*8+j]  (16B-aligned: l15*80 + quad*16 bytes)
        bf16x8 aE = *(const bf16x8*)(E + l15 * 40 + quad * 8);
        // B-frags from VsT: B[k=s_local][n=h]: row h=ht*16+l15, 8 consecutive s
        {
            bf16x8 bv = *(const bf16x8*)(Vbb + (size_t)(0  + l15) * TT + s + quad * 8);
            acc0 = __builtin_amdgcn_mfma_f32_16x16x32_bf16(aE, bv, acc0, 0, 0, 0);
        }
        {
            bf16x8 bv = *(const bf16x8*)(Vbb + (size_t)(16 + l15) * TT + s + quad * 8);
            acc1 = __builtin_amdgcn_mfma_f32_16x16x32_bf16(aE, bv, acc1, 0, 0, 0);
        }
        {
            bf16x8 bv = *(const bf16x8*)(Vbb + (size_t)(32 + l15) * TT + s + quad * 8);
            acc2 = __builtin_amdgcn_mfma_f32_16x16x32_bf16(aE, bv, acc2, 0, 0, 0);
        }
        {
            bf16x8 bv = *(const bf16x8*)(Vbb + (size_t)(48 + l15) * TT + s + quad * 8);
            acc3 = __builtin_amdgcn_mfma_f32_16x16x32_bf16(aE, bv, acc3, 0, 0, 0);
        }
    }
    // Epilogue: C layout rows t=quad*4+r, col h=ht*16+l15
    float* op = OP + (((size_t)z * BB + b) * TT + t0) * HH;
#pragma unroll
    for (int r = 0; r < 4; ++r) {
        size_t ro = (size_t)(quad * 4 + r) * HH + l15;
        op[ro]      = acc0[r];
        op[ro + 16] = acc1[r];
        op[ro + 32] = acc2[r];
        op[ro + 48] = acc3[r];
    }
}

// ---- kernel 5: out = sum_z OP[z] -------------------------------------------
__global__ __launch_bounds__(256) void reduce_kernel(
        const float* __restrict__ OP, float* __restrict__ out) {
    size_t i = (size_t)blockIdx.x * 256 + threadIdx.x;   // float4 units
    const size_t N4 = (size_t)BB * TT * HH / 4;
    if (i >= N4) return;
    const float4* p = (const float4*)OP;
    float4 a = p[i];
#pragma unroll
    for (int zz = 1; zz < SSPLIT; ++zz) {
        float4 v = p[(size_t)zz * N4 + i];
        a.x += v.x; a.y += v.y; a.z += v.z; a.w += v.w;
    }
    ((float4*)out)[i] = a;
}

extern "C" void kernel_launch(void* const* d_in, const int* in_sizes, int n_in,
                              void* d_out, int out_size, void* d_ws, size_t ws_size,
                              hipStream_t stream) {
    const float* x  = (const float*)d_in[0];
    const float* Wq = (const float*)d_in[1];
    const float* Wk = (const float*)d_in[2];
    // d_in[3] (Wv) unused: reference computes v = x @ Wk (faithful quirk).

    const size_t NE = (size_t)BB * TT * HH;     // 2,097,152
    char* wp = (char*)d_ws;
    __bf16* Qb  = (__bf16*)wp;  wp += NE * 2;
    __bf16* Kb  = (__bf16*)wp;  wp += NE * 2;
    __bf16* VsT = (__bf16*)wp;  wp += NE * 2;
    float*  Kf  = (float*)wp;   wp += NE * 4;
    float*  D   = (float*)wp;   wp += (size_t)BB * TT * 4;
    float*  OP  = (float*)wp;   wp += (size_t)SSPLIT * NE * 4;
    float* out = (float*)d_out;

    zeroD_kernel<<<(BB * TT + 255) / 256, 256, 0, stream>>>(D);
    proj_kernel<<<BB * TT / 4, 256, 0, stream>>>(x, Wq, Wk, Qb, Kb, Kf);
    colsum_mfma<<<dim3(TT / 64, BB, TSPLIT), 256, 0, stream>>>(Qb, Kb, D);
    vscale_kernel<<<dim3(TT / 64, BB), 256, 0, stream>>>(Kf, D, VsT);
    out_mfma<<<dim3(TT / 64, BB, SSPLIT), 256, 0, stream>>>(Qb, Kb, VsT, OP);
    reduce_kernel<<<(int)((NE / 4 + 255) / 256), 256, 0, stream>>>(OP, out);
}

// Round 4
// 264.610 us; speedup vs baseline: 9.9950x; 1.7457x over previous
//
#include <hip/hip_runtime.h>
#include <hip/hip_bf16.h>

// Problem constants (from reference): B=8, T=4096, E=16, H=64
#define BB 8
#define TT 4096
#define EE 16
#define HH 64
#define TSPLIT 8   // t-range split for colsum

typedef __attribute__((ext_vector_type(8))) __bf16 bf16x8;  // MFMA A/B frag (4 VGPRs)
typedef __attribute__((ext_vector_type(4))) float f32x4;    // MFMA C/D frag

typedef __attribute__((address_space(3))) void lds_void;
typedef const __attribute__((address_space(1))) void gl_void;

static __device__ __forceinline__ float pow_neg16th_exp(float dot) {
    // exp( dot^(-1/16) ), dot > 0. v_log_f32/v_exp_f32 are base-2.
    float S = __builtin_amdgcn_exp2f(__builtin_amdgcn_logf(dot) * (-1.0f / 16.0f));
    return __builtin_amdgcn_exp2f(S * 1.44269504f);
}

// ---- kernel 0: zero D -------------------------------------------------------
__global__ void zeroD_kernel(float* __restrict__ D) {
    int i = blockIdx.x * 256 + threadIdx.x;
    if (i < BB * TT) D[i] = 0.0f;
}

// ---- kernel 1: Qb = bf16(x@Wq), Kb = bf16(x@Wk) ----------------------------
__global__ __launch_bounds__(256) void proj_kernel(
        const float* __restrict__ x, const float* __restrict__ Wq,
        const float* __restrict__ Wk,
        __bf16* __restrict__ Qb, __bf16* __restrict__ Kb) {
    int tid = threadIdx.x;
    int row = blockIdx.x * 4 + (tid >> 6);
    int h = tid & 63;
    const float* xr = x + (size_t)row * EE;
    float q = 0.f, k = 0.f;
#pragma unroll
    for (int e = 0; e < EE; ++e) {
        float xv = xr[e];
        q += xv * Wq[e * HH + h];
        k += xv * Wk[e * HH + h];
    }
    size_t idx = (size_t)row * HH + h;
    Qb[idx] = (__bf16)q;
    Kb[idx] = (__bf16)k;
}

// ---- kernel 2: D[b,s] += sum_t exp((q_t.k_s)^(-1/16)) via MFMA -------------
// Wave: one 16-wide s-tile, two independent 16-t tiles per iteration (ILP).
// C/D layout (m89): col = lane&15 (=s), row = (lane>>4)*4 + reg (=t).
__global__ __launch_bounds__(256) void colsum_mfma(
        const __bf16* __restrict__ Qb, const __bf16* __restrict__ Kb,
        float* __restrict__ D) {
    int lane = threadIdx.x & 63;
    int w = threadIdx.x >> 6;
    int quad = lane >> 4;
    int l15 = lane & 15;
    int b = blockIdx.y;
    int s0 = blockIdx.x * 64 + w * 16;

    const __bf16* Qbb = Qb + (size_t)b * TT * HH;
    const __bf16* Kbb = Kb + (size_t)b * TT * HH;

    // B-frag: lane holds B[k=quad*8+j][n=l15] = Kb[s0+l15][h=quad*8+j(+32)]
    const __bf16* krow = Kbb + (size_t)(s0 + l15) * HH + quad * 8;
    bf16x8 bk0 = *(const bf16x8*)(krow);
    bf16x8 bk1 = *(const bf16x8*)(krow + 32);

    const int TL = TT / TSPLIT;                 // 512 t per wave
    int t0 = blockIdx.z * TL;
    float csum = 0.f;
    for (int tt = 0; tt < TL; tt += 32) {
        const __bf16* qrow0 = Qbb + (size_t)(t0 + tt + l15) * HH + quad * 8;
        const __bf16* qrow1 = qrow0 + (size_t)16 * HH;
        bf16x8 a00 = *(const bf16x8*)(qrow0);
        bf16x8 a01 = *(const bf16x8*)(qrow0 + 32);
        bf16x8 a10 = *(const bf16x8*)(qrow1);
        bf16x8 a11 = *(const bf16x8*)(qrow1 + 32);
        f32x4 c0 = {0.f, 0.f, 0.f, 0.f};
        f32x4 c1 = {0.f, 0.f, 0.f, 0.f};
        c0 = __builtin_amdgcn_mfma_f32_16x16x32_bf16(a00, bk0, c0, 0, 0, 0);
        c1 = __builtin_amdgcn_mfma_f32_16x16x32_bf16(a10, bk0, c1, 0, 0, 0);
        c0 = __builtin_amdgcn_mfma_f32_16x16x32_bf16(a01, bk1, c0, 0, 0, 0);
        c1 = __builtin_amdgcn_mfma_f32_16x16x32_bf16(a11, bk1, c1, 0, 0, 0);
        csum += pow_neg16th_exp(c0[0]) + pow_neg16th_exp(c0[1])
              + pow_neg16th_exp(c0[2]) + pow_neg16th_exp(c0[3])
              + pow_neg16th_exp(c1[0]) + pow_neg16th_exp(c1[1])
              + pow_neg16th_exp(c1[2]) + pow_neg16th_exp(c1[3]);
    }
    csum += __shfl_xor(csum, 16, 64);
    csum += __shfl_xor(csum, 32, 64);
    if (quad == 0) atomicAdd(&D[(size_t)b * TT + s0 + l15], csum);
}

// ---- kernel 3: VsT[b][h][s] = bf16(Kb[b][s][h]) / D[b][s] ------------------
__global__ __launch_bounds__(256) void vscale_kernel(
        const __bf16* __restrict__ Kb, const float* __restrict__ D,
        __bf16* __restrict__ VsT) {
    __shared__ float tile[64][65];
    int b = blockIdx.y;
    int s0 = blockIdx.x * 64;
    int c = threadIdx.x & 63;
    int rr = threadIdx.x >> 6;
    const __bf16* Kbase = Kb + ((size_t)b * TT + s0) * HH;
    const float* Db = D + (size_t)b * TT + s0;
#pragma unroll
    for (int i = rr; i < 64; i += 4)
        tile[i][c] = (float)Kbase[(size_t)i * HH + c] / Db[i];   // tile[s_local][h]
    __syncthreads();
    __bf16* Vb = VsT + (size_t)b * HH * TT;
#pragma unroll
    for (int i = rr; i < 64; i += 4)
        Vb[(size_t)i * TT + s0 + c] = (__bf16)tile[c][i];        // VsT[h=i][s=s0+c]
}

// ---- kernel 4: OP[z][b][t][h] = sum_{s in slice z} exp(S_ts) * VsT[h][s] ---
// Block = 4 waves x 2 t-tiles = 128 t. Per 32-s chunk: the 8 shared B-frag
// regions (4 QK + 4 PV, 1 KB each) are staged ONCE per block in fragment order
// via global_load_lds (wave-uniform base + lane*16 — m104 semantics), then all
// waves consume with ds_read_b128 at lane*16. E-transpose via per-wave LDS.
__global__ __launch_bounds__(256, 4) void out_mfma(
        const __bf16* __restrict__ Qb, const __bf16* __restrict__ Kb,
        const __bf16* __restrict__ VsT, float* __restrict__ OP) {
    __shared__ __bf16 QKf[4][64][8];        // region sub*2+kh : QK B-frags
    __shared__ __bf16 PVf[4][64][8];        // region ht       : PV B-frags
    __shared__ __bf16 Etile[4][2][16 * 40]; // per-wave, per-tile E transpose

    int lane = threadIdx.x & 63;
    int w = threadIdx.x >> 6;
    int quad = lane >> 4;
    int l15 = lane & 15;
    int b = blockIdx.y;
    int z = blockIdx.z;
    int t0 = blockIdx.x * 128 + w * 32;

    const __bf16* Qbb = Qb + (size_t)b * TT * HH;
    const __bf16* Kbb = Kb + (size_t)b * TT * HH;
    const __bf16* Vbb = VsT + (size_t)b * HH * TT;

    // A-frags for the wave's two t-tiles (persistent)
    bf16x8 aq[2][2];
#pragma unroll
    for (int tile = 0; tile < 2; ++tile) {
        const __bf16* qrow = Qbb + (size_t)(t0 + tile * 16 + l15) * HH + quad * 8;
        aq[tile][0] = *(const bf16x8*)(qrow);
        aq[tile][1] = *(const bf16x8*)(qrow + 32);
    }

    f32x4 acc[2][4];
#pragma unroll
    for (int tile = 0; tile < 2; ++tile)
#pragma unroll
        for (int ht = 0; ht < 4; ++ht)
            acc[tile][ht] = (f32x4){0.f, 0.f, 0.f, 0.f};

    // This wave stages region w (QK: sub=w>>1, kh=w&1) and region w+4 (PV: ht=w).
    // Stager lane i fetches exactly what consumer lane i reads (slot = lane*16B).
    const __bf16* gA = Kbb + (size_t)((w >> 1) * 16 + l15) * HH + quad * 8 + (w & 1) * 32;
    const __bf16* gB = Vbb + (size_t)(w * 16 + l15) * TT + quad * 8;

    const int SL = TT / gridDim.z;
    int s0z = z * SL;
    for (int s = s0z; s < s0z + SL; s += 32) {
        __builtin_amdgcn_global_load_lds((gl_void*)(gA + (size_t)s * HH),
                                         (lds_void*)&QKf[w][0][0], 16, 0, 0);
        __builtin_amdgcn_global_load_lds((gl_void*)(gB + s),
                                         (lds_void*)&PVf[w][0][0], 16, 0, 0);
        __builtin_amdgcn_s_waitcnt(0x0f70);   // vmcnt(0): this wave's stages done
        __syncthreads();                      // all regions visible

        bf16x8 bk[2][2], bv[4];
#pragma unroll
        for (int sub = 0; sub < 2; ++sub)
#pragma unroll
            for (int kh = 0; kh < 2; ++kh)
                bk[sub][kh] = *(const bf16x8*)&QKf[sub * 2 + kh][lane][0];
#pragma unroll
        for (int ht = 0; ht < 4; ++ht)
            bv[ht] = *(const bf16x8*)&PVf[ht][lane][0];

#pragma unroll
        for (int tile = 0; tile < 2; ++tile) {
#pragma unroll
            for (int sub = 0; sub < 2; ++sub) {
                f32x4 c = {0.f, 0.f, 0.f, 0.f};
                c = __builtin_amdgcn_mfma_f32_16x16x32_bf16(aq[tile][0], bk[sub][0], c, 0, 0, 0);
                c = __builtin_amdgcn_mfma_f32_16x16x32_bf16(aq[tile][1], bk[sub][1], c, 0, 0, 0);
                // C layout: row t_local = quad*4+r, col s_local = sub*16+l15
#pragma unroll
                for (int r = 0; r < 4; ++r)
                    Etile[w][tile][(quad * 4 + r) * 40 + sub * 16 + l15] =
                        (__bf16)pow_neg16th_exp(c[r]);
            }
        }
        __builtin_amdgcn_s_waitcnt(0xc07f);   // lgkmcnt(0): wave's E writes visible
#pragma unroll
        for (int tile = 0; tile < 2; ++tile) {
            // A-frag from E: A[m=l15][k=quad*8+j]
            bf16x8 aE = *(const bf16x8*)&Etile[w][tile][l15 * 40 + quad * 8];
#pragma unroll
            for (int ht = 0; ht < 4; ++ht)
                acc[tile][ht] = __builtin_amdgcn_mfma_f32_16x16x32_bf16(aE, bv[ht], acc[tile][ht], 0, 0, 0);
        }
        __syncthreads();                      // protect regions before next stage
    }

    // Epilogue: C layout rows t = t0 + tile*16 + quad*4 + r, col h = ht*16 + l15
    float* op = OP + (((size_t)z * BB + b) * TT + t0) * HH;
#pragma unroll
    for (int tile = 0; tile < 2; ++tile) {
#pragma unroll
        for (int r = 0; r < 4; ++r) {
            size_t ro = (size_t)(tile * 16 + quad * 4 + r) * HH + l15;
            op[ro]      = acc[tile][0][r];
            op[ro + 16] = acc[tile][1][r];
            op[ro + 32] = acc[tile][2][r];
            op[ro + 48] = acc[tile][3][r];
        }
    }
}

// ---- kernel 5: out = sum_z OP[z] -------------------------------------------
__global__ __launch_bounds__(256) void reduce_kernel(
        const float* __restrict__ OP, float* __restrict__ out, int nslice) {
    size_t i = (size_t)blockIdx.x * 256 + threadIdx.x;   // float4 units
    const size_t N4 = (size_t)BB * TT * HH / 4;
    if (i >= N4) return;
    const float4* p = (const float4*)OP;
    float4 a = p[i];
    for (int zz = 1; zz < nslice; ++zz) {
        float4 v = p[(size_t)zz * N4 + i];
        a.x += v.x; a.y += v.y; a.z += v.z; a.w += v.w;
    }
    ((float4*)out)[i] = a;
}

extern "C" void kernel_launch(void* const* d_in, const int* in_sizes, int n_in,
                              void* d_out, int out_size, void* d_ws, size_t ws_size,
                              hipStream_t stream) {
    const float* x  = (const float*)d_in[0];
    const float* Wq = (const float*)d_in[1];
    const float* Wk = (const float*)d_in[2];
    // d_in[3] (Wv) unused: reference computes v = x @ Wk (faithful quirk).

    const size_t NE = (size_t)BB * TT * HH;     // 2,097,152
    // Pick SSPLIT for out pass based on workspace capacity (OP = nslice*NE*4 B).
    size_t base = NE * 2 * 3 + (size_t)BB * TT * 4;
    int nslice = 8;
    if (base + (size_t)8 * NE * 4 > ws_size) nslice = 4;
    if (base + (size_t)4 * NE * 4 > ws_size) nslice = 2;

    char* wp = (char*)d_ws;
    __bf16* Qb  = (__bf16*)wp;  wp += NE * 2;
    __bf16* Kb  = (__bf16*)wp;  wp += NE * 2;
    __bf16* VsT = (__bf16*)wp;  wp += NE * 2;
    float*  D   = (float*)wp;   wp += (size_t)BB * TT * 4;
    float*  OP  = (float*)wp;
    float* out = (float*)d_out;

    zeroD_kernel<<<(BB * TT + 255) / 256, 256, 0, stream>>>(D);
    proj_kernel<<<BB * TT / 4, 256, 0, stream>>>(x, Wq, Wk, Qb, Kb);
    colsum_mfma<<<dim3(TT / 64, BB, TSPLIT), 256, 0, stream>>>(Qb, Kb, D);
    vscale_kernel<<<dim3(TT / 64, BB), 256, 0, stream>>>(Kb, D, VsT);
    out_mfma<<<dim3(TT / 128, BB, nslice), 256, 0, stream>>>(Qb, Kb, VsT, OP);
    reduce_kernel<<<(int)((NE / 4 + 255) / 256), 256, 0, stream>>>(OP, out, nslice);
}

// Round 5
// 190.152 us; speedup vs baseline: 13.9088x; 1.3916x over previous
//
#include <hip/hip_runtime.h>
#include <hip/hip_bf16.h>

// Problem constants (from reference): B=8, T=4096, E=16, H=64
#define BB 8
#define TT 4096
#define EE 16
#define HH 64
#define TCH 16     // colsum: total t-chunks (gridDim.z=4 x 4 waves)

typedef __attribute__((ext_vector_type(8))) __bf16 bf16x8;  // MFMA A/B frag (4 VGPRs)
typedef __attribute__((ext_vector_type(4))) float f32x4;    // MFMA C/D frag

typedef __attribute__((address_space(3))) void lds_void;
typedef const __attribute__((address_space(1))) void gl_void;

static __device__ __forceinline__ float pow_neg16th_exp(float dot) {
    // e^(dot^(-1/16)) = exp2( exp2( log2(dot)*(-1/16) + log2(log2 e) ) ), dot > 0.
    // 3 HW transcendentals + 1 FMA (2^0.5287664 = log2 e folds the scale mul).
    float v = __builtin_fmaf(__builtin_amdgcn_logf(dot), -0.0625f, 0.5287663729448977f);
    return __builtin_amdgcn_exp2f(__builtin_amdgcn_exp2f(v));
}

// ---- kernel 0: zero D -------------------------------------------------------
__global__ void zeroD_kernel(float* __restrict__ D) {
    int i = blockIdx.x * 256 + threadIdx.x;
    if (i < BB * TT) D[i] = 0.0f;
}

// ---- kernel 1: Qb = bf16(x@Wq), Kb = bf16(x@Wk) ----------------------------
__global__ __launch_bounds__(256) void proj_kernel(
        const float* __restrict__ x, const float* __restrict__ Wq,
        const float* __restrict__ Wk,
        __bf16* __restrict__ Qb, __bf16* __restrict__ Kb) {
    int tid = threadIdx.x;
    int row = blockIdx.x * 4 + (tid >> 6);
    int h = tid & 63;
    const float* xr = x + (size_t)row * EE;
    float q = 0.f, k = 0.f;
#pragma unroll
    for (int e = 0; e < EE; ++e) {
        float xv = xr[e];
        q += xv * Wq[e * HH + h];
        k += xv * Wk[e * HH + h];
    }
    size_t idx = (size_t)row * HH + h;
    Qb[idx] = (__bf16)q;
    Kb[idx] = (__bf16)k;
}

// ---- kernel 2: D[b,s] += sum_t exp((q_t.k_s)^(-1/16)) via MFMA -------------
// Register-blocked: wave holds 4 persistent s-tiles (64 s) in B-frags and
// streams 2 t-tiles/iter -> Q traffic /4 vs R4, 8 MFMA-pairs + 32 exp per iter.
// All 4 waves of a block share the same s-range (B-frags identical), each takes
// a different t-chunk. C/D layout (m89): col = lane&15 (=s), row = quad*4+reg.
__global__ __launch_bounds__(256, 4) void colsum_mfma(
        const __bf16* __restrict__ Qb, const __bf16* __restrict__ Kb,
        float* __restrict__ D) {
    int lane = threadIdx.x & 63;
    int w = threadIdx.x >> 6;
    int quad = lane >> 4;
    int l15 = lane & 15;
    int b = blockIdx.y;
    int s0 = blockIdx.x * 64;

    const __bf16* Qbb = Qb + (size_t)b * TT * HH;
    const __bf16* Kbb = Kb + (size_t)b * TT * HH;

    bf16x8 bk[4][2];
#pragma unroll
    for (int st = 0; st < 4; ++st) {
        const __bf16* krow = Kbb + (size_t)(s0 + st * 16 + l15) * HH + quad * 8;
        bk[st][0] = *(const bf16x8*)(krow);
        bk[st][1] = *(const bf16x8*)(krow + 32);
    }

    const int TL = TT / TCH;                  // 256 t per wave
    int t0 = (blockIdx.z * 4 + w) * TL;
    float csum[4] = {0.f, 0.f, 0.f, 0.f};
    for (int tt = 0; tt < TL; tt += 32) {
        const __bf16* qrow0 = Qbb + (size_t)(t0 + tt + l15) * HH + quad * 8;
        bf16x8 a00 = *(const bf16x8*)(qrow0);
        bf16x8 a01 = *(const bf16x8*)(qrow0 + 32);
        bf16x8 a10 = *(const bf16x8*)(qrow0 + 16 * HH);
        bf16x8 a11 = *(const bf16x8*)(qrow0 + 16 * HH + 32);
#pragma unroll
        for (int st = 0; st < 4; ++st) {
            f32x4 c0 = {0.f, 0.f, 0.f, 0.f};
            f32x4 c1 = {0.f, 0.f, 0.f, 0.f};
            c0 = __builtin_amdgcn_mfma_f32_16x16x32_bf16(a00, bk[st][0], c0, 0, 0, 0);
            c1 = __builtin_amdgcn_mfma_f32_16x16x32_bf16(a10, bk[st][0], c1, 0, 0, 0);
            c0 = __builtin_amdgcn_mfma_f32_16x16x32_bf16(a01, bk[st][1], c0, 0, 0, 0);
            c1 = __builtin_amdgcn_mfma_f32_16x16x32_bf16(a11, bk[st][1], c1, 0, 0, 0);
            csum[st] += pow_neg16th_exp(c0[0]) + pow_neg16th_exp(c0[1])
                      + pow_neg16th_exp(c0[2]) + pow_neg16th_exp(c0[3])
                      + pow_neg16th_exp(c1[0]) + pow_neg16th_exp(c1[1])
                      + pow_neg16th_exp(c1[2]) + pow_neg16th_exp(c1[3]);
        }
    }
#pragma unroll
    for (int st = 0; st < 4; ++st) {
        float r = csum[st];
        r += __shfl_xor(r, 16, 64);
        r += __shfl_xor(r, 32, 64);
        if (quad == 0) atomicAdd(&D[(size_t)b * TT + s0 + st * 16 + l15], r);
    }
}

// ---- kernel 3: VsT[b][h][s] = bf16(Kb[b][s][h]) / D[b][s] ------------------
__global__ __launch_bounds__(256) void vscale_kernel(
        const __bf16* __restrict__ Kb, const float* __restrict__ D,
        __bf16* __restrict__ VsT) {
    __shared__ float tile[64][65];
    int b = blockIdx.y;
    int s0 = blockIdx.x * 64;
    int c = threadIdx.x & 63;
    int rr = threadIdx.x >> 6;
    const __bf16* Kbase = Kb + ((size_t)b * TT + s0) * HH;
    const float* Db = D + (size_t)b * TT + s0;
#pragma unroll
    for (int i = rr; i < 64; i += 4)
        tile[i][c] = (float)Kbase[(size_t)i * HH + c] / Db[i];   // tile[s_local][h]
    __syncthreads();
    __bf16* Vb = VsT + (size_t)b * HH * TT;
#pragma unroll
    for (int i = rr; i < 64; i += 4)
        Vb[(size_t)i * TT + s0 + c] = (__bf16)tile[c][i];        // VsT[h=i][s=s0+c]
}

// ---- kernel 4: OP[z][b][t][h] = sum_{s in slice z} exp(S_ts) * VsT[h][s] ---
// Double-buffered block staging: stage chunk i+1 into buf^1 at top of iter i,
// wait vmcnt(2) (= this wave's chunk-i loads, issued one FULL iteration ago),
// raw s_barrier (no vmcnt(0) drain — the m97 stall). End-of-iter: lgkmcnt(0)
// (my LDS reads done) + raw s_barrier makes buf safe to overwrite next iter.
__global__ __launch_bounds__(256, 4) void out_mfma(
        const __bf16* __restrict__ Qb, const __bf16* __restrict__ Kb,
        const __bf16* __restrict__ VsT, float* __restrict__ OP) {
    __shared__ __bf16 QKf[2][4][64][8];     // [buf][region sub*2+kh][lane][8]
    __shared__ __bf16 PVf[2][4][64][8];     // [buf][region ht][lane][8]
    __shared__ __bf16 Etile[4][2][16 * 40]; // per-wave, per-tile E transpose

    int lane = threadIdx.x & 63;
    int w = threadIdx.x >> 6;
    int quad = lane >> 4;
    int l15 = lane & 15;
    int b = blockIdx.y;
    int z = blockIdx.z;
    int t0 = blockIdx.x * 128 + w * 32;

    const __bf16* Qbb = Qb + (size_t)b * TT * HH;
    const __bf16* Kbb = Kb + (size_t)b * TT * HH;
    const __bf16* Vbb = VsT + (size_t)b * HH * TT;

    bf16x8 aq[2][2];
#pragma unroll
    for (int tile = 0; tile < 2; ++tile) {
        const __bf16* qrow = Qbb + (size_t)(t0 + tile * 16 + l15) * HH + quad * 8;
        aq[tile][0] = *(const bf16x8*)(qrow);
        aq[tile][1] = *(const bf16x8*)(qrow + 32);
    }

    f32x4 acc[2][4];
#pragma unroll
    for (int tile = 0; tile < 2; ++tile)
#pragma unroll
        for (int ht = 0; ht < 4; ++ht)
            acc[tile][ht] = (f32x4){0.f, 0.f, 0.f, 0.f};

    // Wave stages region w (QK: sub=w>>1, kh=w&1) and region w (PV: ht=w).
    const __bf16* gA = Kbb + (size_t)((w >> 1) * 16 + l15) * HH + quad * 8 + (w & 1) * 32;
    const __bf16* gB = Vbb + (size_t)(w * 16 + l15) * TT + quad * 8;

    const int SL = TT / gridDim.z;
    int s0z = z * SL, send = s0z + SL;

    // Prologue: stage chunk 0 into buf 0.
    __builtin_amdgcn_global_load_lds((gl_void*)(gA + (size_t)s0z * HH),
                                     (lds_void*)&QKf[0][w][0][0], 16, 0, 0);
    __builtin_amdgcn_global_load_lds((gl_void*)(gB + s0z),
                                     (lds_void*)&PVf[0][w][0][0], 16, 0, 0);

    int buf = 0;
    for (int s = s0z; s < send; s += 32) {
        int snext = (s + 32 < send) ? (s + 32) : s0z;   // last iter: dummy reload
        int nb = buf ^ 1;
        __builtin_amdgcn_global_load_lds((gl_void*)(gA + (size_t)snext * HH),
                                         (lds_void*)&QKf[nb][w][0][0], 16, 0, 0);
        __builtin_amdgcn_global_load_lds((gl_void*)(gB + snext),
                                         (lds_void*)&PVf[nb][w][0][0], 16, 0, 0);
        __builtin_amdgcn_s_waitcnt(0x0f72);   // vmcnt(2): all but newest 2 done
        __builtin_amdgcn_s_barrier();         // buf's regions visible to all waves

        bf16x8 bk[2][2], bv[4];
#pragma unroll
        for (int sub = 0; sub < 2; ++sub)
#pragma unroll
            for (int kh = 0; kh < 2; ++kh)
                bk[sub][kh] = *(const bf16x8*)&QKf[buf][sub * 2 + kh][lane][0];
#pragma unroll
        for (int ht = 0; ht < 4; ++ht)
            bv[ht] = *(const bf16x8*)&PVf[buf][ht][lane][0];

#pragma unroll
        for (int tile = 0; tile < 2; ++tile) {
#pragma unroll
            for (int sub = 0; sub < 2; ++sub) {
                f32x4 c = {0.f, 0.f, 0.f, 0.f};
                c = __builtin_amdgcn_mfma_f32_16x16x32_bf16(aq[tile][0], bk[sub][0], c, 0, 0, 0);
                c = __builtin_amdgcn_mfma_f32_16x16x32_bf16(aq[tile][1], bk[sub][1], c, 0, 0, 0);
                // C layout: row t_local = quad*4+r, col s_local = sub*16+l15
#pragma unroll
                for (int r = 0; r < 4; ++r)
                    Etile[w][tile][(quad * 4 + r) * 40 + sub * 16 + l15] =
                        (__bf16)pow_neg16th_exp(c[r]);
            }
        }
        __builtin_amdgcn_s_waitcnt(0xc07f);   // lgkmcnt(0): wave's E writes visible
#pragma unroll
        for (int tile = 0; tile < 2; ++tile) {
            bf16x8 aE = *(const bf16x8*)&Etile[w][tile][l15 * 40 + quad * 8];
#pragma unroll
            for (int ht = 0; ht < 4; ++ht)
                acc[tile][ht] = __builtin_amdgcn_mfma_f32_16x16x32_bf16(aE, bv[ht], acc[tile][ht], 0, 0, 0);
        }
        __builtin_amdgcn_s_waitcnt(0xc07f);   // all my LDS reads complete
        __builtin_amdgcn_s_barrier();         // buf now safe to overwrite
        buf = nb;
    }

    // Epilogue: C layout rows t = t0 + tile*16 + quad*4 + r, col h = ht*16 + l15
    float* op = OP + (((size_t)z * BB + b) * TT + t0) * HH;
#pragma unroll
    for (int tile = 0; tile < 2; ++tile) {
#pragma unroll
        for (int r = 0; r < 4; ++r) {
            size_t ro = (size_t)(tile * 16 + quad * 4 + r) * HH + l15;
            op[ro]      = acc[tile][0][r];
            op[ro + 16] = acc[tile][1][r];
            op[ro + 32] = acc[tile][2][r];
            op[ro + 48] = acc[tile][3][r];
        }
    }
}

// ---- kernel 5: out = sum_z OP[z] -------------------------------------------
__global__ __launch_bounds__(256) void reduce_kernel(
        const float* __restrict__ OP, float* __restrict__ out, int nslice) {
    size_t i = (size_t)blockIdx.x * 256 + threadIdx.x;   // float4 units
    const size_t N4 = (size_t)BB * TT * HH / 4;
    if (i >= N4) return;
    const float4* p = (const float4*)OP;
    float4 a = p[i];
    for (int zz = 1; zz < nslice; ++zz) {
        float4 v = p[(size_t)zz * N4 + i];
        a.x += v.x; a.y += v.y; a.z += v.z; a.w += v.w;
    }
    ((float4*)out)[i] = a;
}

extern "C" void kernel_launch(void* const* d_in, const int* in_sizes, int n_in,
                              void* d_out, int out_size, void* d_ws, size_t ws_size,
                              hipStream_t stream) {
    const float* x  = (const float*)d_in[0];
    const float* Wq = (const float*)d_in[1];
    const float* Wk = (const float*)d_in[2];
    // d_in[3] (Wv) unused: reference computes v = x @ Wk (faithful quirk).

    const size_t NE = (size_t)BB * TT * HH;     // 2,097,152
    size_t base = NE * 2 * 3 + (size_t)BB * TT * 4;
    int nslice = 8;
    if (base + (size_t)8 * NE * 4 > ws_size) nslice = 4;
    if (base + (size_t)4 * NE * 4 > ws_size) nslice = 2;

    char* wp = (char*)d_ws;
    __bf16* Qb  = (__bf16*)wp;  wp += NE * 2;
    __bf16* Kb  = (__bf16*)wp;  wp += NE * 2;
    __bf16* VsT = (__bf16*)wp;  wp += NE * 2;
    float*  D   = (float*)wp;   wp += (size_t)BB * TT * 4;
    float*  OP  = (float*)wp;
    float* out = (float*)d_out;

    zeroD_kernel<<<(BB * TT + 255) / 256, 256, 0, stream>>>(D);
    proj_kernel<<<BB * TT / 4, 256, 0, stream>>>(x, Wq, Wk, Qb, Kb);
    colsum_mfma<<<dim3(TT / 64, BB, TCH / 4), 256, 0, stream>>>(Qb, Kb, D);
    vscale_kernel<<<dim3(TT / 64, BB), 256, 0, stream>>>(Kb, D, VsT);
    out_mfma<<<dim3(TT / 128, BB, nslice), 256, 0, stream>>>(Qb, Kb, VsT, OP);
    reduce_kernel<<<(int)((NE / 4 + 255) / 256), 256, 0, stream>>>(OP, out, nslice);
}